// Round 15
// baseline (197.512 us; speedup 1.0000x reference)
//
#include <hip/hip_runtime.h>
#include <hip/hip_bf16.h>
#include <stdint.h>

#define DI __device__ __forceinline__

typedef float f32x4 __attribute__((ext_vector_type(4)));
typedef float f32x2 __attribute__((ext_vector_type(2)));
typedef short bf16x8 __attribute__((ext_vector_type(8)));

constexpr int BB = 8192, TT = 128, DD = 16, HH = 32;
constexpr float kEPS = 1e-5f;
constexpr float kLOG2E = 1.44269504088896340736f;

// ---------------- helpers ----------------
DI float rcpf_(float x) { return __builtin_amdgcn_rcpf(x); }
DI float exp2f_(float x) { return __builtin_amdgcn_exp2f(x); }
DI float sigm(float x) { return rcpf_(1.0f + exp2f_(-kLOG2E * x)); }

// Full-rate polynomial exp2: runs on the main VALU pipe, NOT the 1/8-rate
// trans unit -> overlaps with native v_exp/v_rcp issue. Range-reduce with
// rndne (f in [-1/2,1/2]), degree-4 Taylor (rel err ~6e-5 << bf16 eps),
// exponent splice via integer add (safe: gate preacts |x| < ~40).
DI float exp2p(float x) {
  float i_f;
  asm("v_rndne_f32 %0, %1" : "=v"(i_f) : "v"(x));
  float f = x - i_f;
  int i = (int)i_f;
  float p = 0.00961812911f;                       // ln2^4/24
  p = __builtin_fmaf(f, p, 0.05550410866f);       // ln2^3/6
  p = __builtin_fmaf(f, p, 0.24022650696f);       // ln2^2/2
  p = __builtin_fmaf(f, p, 0.69314718056f);       // ln2
  p = __builtin_fmaf(f, p, 1.0f);
  union { float fv; int iv; } u;
  u.fv = p;
  u.iv += (i << 23);                              // ldexp(p, i)
  return u.fv;
}

DI uint32_t cvtpk(float lo, float hi) {
  uint32_t r;
  asm("v_cvt_pk_bf16_f32 %0, %1, %2" : "=v"(r) : "v"(lo), "v"(hi));
  return r;
}

DI f32x4 mfma_(bf16x8 a, bf16x8 b, f32x4 c) {
  return __builtin_amdgcn_mfma_f32_16x16x32_bf16(a, b, c, 0, 0, 0);
}

union U4 { uint4 q; bf16x8 v; uint32_t u[4]; };

// ---------------- weight prep (per net, device impl) ----------------
// Identical math to round 14 (passed): pi k-permutation, exp2 pre-scaling,
// BN folded into emb, delta outW/outB pre-scaled by -log2e.
__device__ void prep_impl(const float* Wih0, const float* Whh0,
                          const float* bih0, const float* bhh0,
                          const float* Wih1, const float* Whh1,
                          const float* bih1, const float* bhh1,
                          const float* embW, const float* embB,
                          const float* bng, const float* bnb,
                          const float* bnm, const float* bnv,
                          const float* outW, const float* outB,
                          int outDim, uint8_t* wsbase) {
  int tid = threadIdx.x;
  uint16_t* W = (uint16_t*)wsbase;
  float* bias = (float*)(wsbase + 27648);
  auto cvt = [](float f) -> uint16_t {
    union { float f; uint32_t u; } v; v.f = f;
    uint32_t u = v.u;
    return (uint16_t)((u + 0x7FFF + ((u >> 16) & 1)) >> 16);  // RNE
  };
  const float oscale = (outDim == 16) ? -kLOG2E : 1.0f;
  for (int idx = tid; idx < 27 * 64; idx += 256) {
    int tile = idx >> 6, l = idx & 63, cc = l & 15, gg = l >> 4;
    uint16_t* dst = W + (size_t)idx * 8;
    if (tile < 24) {
      const float* mats[4] = {Wih0, Whh0, Wih1, Whh1};
      const float* src = mats[tile / 6];
      int sub = tile % 6;                   // r0 r1 z0 z1 n0 n1
      int row = sub * 16 + cc;
      float sc = (sub < 4) ? -kLOG2E : 2.0f * kLOG2E;
#pragma unroll
      for (int j = 0; j < 8; ++j) {
        int k = (j < 4) ? 4 * gg + j : 16 + 4 * gg + (j - 4);  // pi
        dst[j] = cvt(src[row * 32 + k] * sc);
      }
    } else if (tile < 26) {
      int row = (tile - 24) * 16 + cc;
      float a = bng[row] * rsqrtf(bnv[row] + kEPS);
#pragma unroll
      for (int j = 0; j < 8; ++j) {
        int k = (j < 4) ? 4 * gg + j : 16 + 4 * gg + (j - 4);  // pi
        dst[j] = cvt(embW[row * 32 + k] * a);
      }
    } else {
      int rrow = (cc < outDim) ? cc : 0;
      float sc = (cc < outDim) ? oscale : 0.0f;
#pragma unroll
      for (int j = 0; j < 8; ++j) {
        int k = (j < 4) ? 4 * gg + j : 16 + 4 * gg + (j - 4);  // pi
        dst[j] = cvt(outW[rrow * 32 + k] * sc);
      }
    }
  }
  for (int idx = tid; idx < 304; idx += 256) {
    int tile = idx >> 4, n = idx & 15;
    float v;
    if (tile < 8) {
      if (tile < 4)      v = (bih0[tile * 16 + n] + bhh0[tile * 16 + n]) * (-kLOG2E);
      else if (tile < 6) v = bih0[64 + (tile - 4) * 16 + n] * (2.0f * kLOG2E);
      else               v = bhh0[64 + (tile - 6) * 16 + n] * (2.0f * kLOG2E);
    } else if (tile < 16) {
      int tt = tile - 8;
      if (tt < 4)        v = (bih1[tt * 16 + n] + bhh1[tt * 16 + n]) * (-kLOG2E);
      else if (tt < 6)   v = bih1[64 + (tt - 4) * 16 + n] * (2.0f * kLOG2E);
      else               v = bhh1[64 + (tt - 6) * 16 + n] * (2.0f * kLOG2E);
    } else if (tile < 18) {
      int nn = (tile - 16) * 16 + n;
      float a = bng[nn] * rsqrtf(bnv[nn] + kEPS);
      v = a * (embB[nn] - bnm[nn]) + bnb[nn];
    } else {
      v = (n < outDim) ? outB[n] * oscale : 0.0f;
    }
    bias[idx] = v;
  }
}

// One launch, 2 blocks: block 0 = price net, block 1 = delta net.
__global__ void prep_both(
    const float* pW0, const float* pWh0, const float* pb0, const float* pbh0,
    const float* pW1, const float* pWh1, const float* pb1, const float* pbh1,
    const float* pe,  const float* peb,  const float* pg,  const float* pbb,
    const float* pm,  const float* pv,   const float* po,  const float* pob,
    const float* dW0, const float* dWh0, const float* db0, const float* dbh0,
    const float* dW1, const float* dWh1, const float* db1, const float* dbh1,
    const float* de,  const float* deb,  const float* dg,  const float* dbb,
    const float* dm,  const float* dv,   const float* doW, const float* dob,
    uint8_t* ws) {
  if (blockIdx.x == 0)
    prep_impl(pW0, pWh0, pb0, pbh0, pW1, pWh1, pb1, pbh1,
              pe, peb, pg, pbb, pm, pv, po, pob, 1, ws);
  else
    prep_impl(dW0, dWh0, db0, dbh0, dW1, dWh1, db1, dbh1,
              de, deb, dg, dbb, dm, dv, doW, dob, 16, ws + 32768);
}

// ---- fused RNN + heads: depth-4 pipeline, dual-pipe transcendentals ------
// One wave = 16 rows x 1 net. Iteration computes L0(t) | L1(t+1) | e(t+2) |
// o/store(t+3). Gate r/z exponentials run as full-rate FMA polys (VALU
// pipe); n-exponential, SiLU, out-sigmoid, all rcps stay on the 1/8-rate
// trans unit -> the two pipes overlap instead of queueing on one.
__global__ __launch_bounds__(64, 1) void rnn_fused(
    const float* __restrict__ S, const float* __restrict__ gS,
    const float* __restrict__ hp0, const float* __restrict__ hd0,
    const uint8_t* __restrict__ ws, float* __restrict__ out) {
  const int lane = threadIdx.x & 63;
  const int net = blockIdx.x & 1;                 // 0 = price, 1 = delta
  const int b0 = (blockIdx.x >> 1) * 16;
  const int c = lane & 15, g = lane >> 4;

  const uint16_t* W = (const uint16_t*)(ws + net * 32768);
  const float* bias = (const float*)(ws + net * 32768 + 27648);
  const float* hsrc = net ? hd0 : hp0;

  bf16x8 Wt[27];
#pragma unroll
  for (int t = 0; t < 27; ++t)
    Wt[t] = *(const bf16x8*)(W + (t * 64 + lane) * 8);
  f32x4 Bq[19];
#pragma unroll
  for (int t = 0; t < 19; ++t)
    Bq[t] = *(const f32x4*)(bias + t * 16 + 4 * g);

  auto packB = [&](const float (&v)[8]) -> bf16x8 {
    U4 t;
    t.u[0] = cvtpk(v[0], v[1]); t.u[1] = cvtpk(v[2], v[3]);
    t.u[2] = cvtpk(v[4], v[5]); t.u[3] = cvtpk(v[6], v[7]);
    return t.v;
  };

  auto mfmaGRU = [&](int wih, int whh, int bb, bf16x8 xf, bf16x8 hf,
                     f32x4 (&A)[8]) {
    A[0] = mfma_(Wt[wih + 0], xf, Bq[bb + 0]); A[0] = mfma_(Wt[whh + 0], hf, A[0]);
    A[1] = mfma_(Wt[wih + 1], xf, Bq[bb + 1]); A[1] = mfma_(Wt[whh + 1], hf, A[1]);
    A[2] = mfma_(Wt[wih + 2], xf, Bq[bb + 2]); A[2] = mfma_(Wt[whh + 2], hf, A[2]);
    A[3] = mfma_(Wt[wih + 3], xf, Bq[bb + 3]); A[3] = mfma_(Wt[whh + 3], hf, A[3]);
    A[4] = mfma_(Wt[wih + 4], xf, Bq[bb + 4]);
    A[5] = mfma_(Wt[wih + 5], xf, Bq[bb + 5]);
    A[6] = mfma_(Wt[whh + 4], hf, Bq[bb + 6]);
    A[7] = mfma_(Wt[whh + 5], hf, Bq[bb + 7]);
  };

  // gates: r/z exponentials on the VALU pipe (exp2p), n-exp + rcps native.
  auto gates = [&](const f32x4 (&A)[8], float (&hC)[8]) {
    const f32x2 one = {1.0f, 1.0f};
#pragma unroll
    for (int r = 0; r < 4; ++r) {
      f32x2 ni = {A[4][r], A[5][r]};
      f32x2 nh = {A[6][r], A[7][r]};
      f32x2 hv = {hC[r], hC[4 + r]};
      f32x2 era = {exp2p(A[0][r]), exp2p(A[1][r])};   // VALU pipe
      f32x2 Ez  = {exp2p(A[2][r]), exp2p(A[3][r])};   // VALU pipe
      f32x2 t1 = one + era;
      f32x2 rg = {rcpf_(t1[0]), rcpf_(t1[1])};        // trans pipe
      f32x2 w = ni + rg * nh;
      f32x2 En = {exp2f_(w[0]), exp2f_(w[1])};        // trans pipe
      f32x2 num = (hv - Ez) + En * (hv + Ez);
      f32x2 den = (one + En) * (one + Ez);
      f32x2 rd = {rcpf_(den[0]), rcpf_(den[1])};      // trans pipe
      f32x2 res = num * rd;
      hC[r] = res[0]; hC[4 + r] = res[1];
    }
  };

  auto silu = [&](const f32x4& e0, const f32x4& e1, float (&es)[8]) {
#pragma unroll
    for (int r = 0; r < 4; ++r) {
      float a = e0[r], b = e1[r];
      es[r]     = a * sigm(a);
      es[4 + r] = b * sigm(b);
    }
  };

  auto storeO = [&](const f32x4& o, int th) {
    if (net == 0) {
      if (lane < 16) out[(size_t)(b0 + c) * TT + th] = o[0];
    } else {
      f32x4 so;                       // outW prescaled: sig = rcp(1+exp2)
#pragma unroll
      for (int r = 0; r < 4; ++r) so[r] = rcpf_(1.0f + exp2f_(o[r]));
      *(f32x4*)(out + (size_t)BB * TT +
                ((size_t)(b0 + c) * TT + th) * DD + 4 * g) = so;
    }
  };

  auto loadState = [&](const float* row, float (&hC)[8]) -> bf16x8 {
    f32x4 a = *(const f32x4*)(row + 4 * g);
    f32x4 b = *(const f32x4*)(row + 16 + 4 * g);
#pragma unroll
    for (int r = 0; r < 4; ++r) { hC[r] = a[r]; hC[4 + r] = b[r]; }
    U4 t;
    t.u[0] = cvtpk(a[0], a[1]); t.u[1] = cvtpk(a[2], a[3]);
    t.u[2] = cvtpk(b[0], b[1]); t.u[3] = cvtpk(b[2], b[3]);
    return t.v;
  };

  auto mkX = [&](f32x4 sv, float gsv) -> bf16x8 {
    uint32_t pkg = cvtpk(gsv, gsv);
    U4 t;
    t.u[0] = cvtpk(sv[0], sv[1]);
    t.u[1] = cvtpk(sv[2], sv[3]);
    t.u[2] = pkg;
    t.u[3] = pkg;
    return t.v;
  };

  const float* Sbase  = S  + (size_t)(b0 + c) * TT * DD + 4 * g;
  const float* gSbase = gS + (size_t)(b0 + c) * TT;

  // pipeline state
  float h0C[8], h1C[8], es[8];
  bf16x8 h0B = loadState(hsrc + (size_t)(b0 + c) * HH, h0C);
  bf16x8 h1B = loadState(hsrc + ((size_t)BB + b0 + c) * HH, h1C);
  bf16x8 ef, xB;
  f32x4 A0[8], A1[8], e0, e1, o;

  // x rolling registers: xB = x(t); xr0 = raw x(t-1); xr1 = raw x(t-2)
  f32x4 xr0, xr1;
  float gr0, gr1;
  xB  = mkX(*(const f32x4*)(Sbase + (size_t)(TT - 1) * DD), gSbase[TT - 1]);
  xr0 = *(const f32x4*)(Sbase + (size_t)(TT - 2) * DD); gr0 = gSbase[TT - 2];
  xr1 = *(const f32x4*)(Sbase + (size_t)(TT - 3) * DD); gr1 = gSbase[TT - 3];
  auto rollX = [&](int tn) {
    xB = mkX(xr0, gr0);
    xr0 = xr1; gr0 = gr1;
    if (tn < 0) tn = 0;
    xr1 = *(const f32x4*)(Sbase + (size_t)tn * DD); gr1 = gSbase[tn];
  };

  // ---- prologue P0 (t = TT-1): L0 only ----
  mfmaGRU(0, 6, 0, xB, h0B, A0);
  gates(A0, h0C);
  h0B = packB(h0C);
  rollX(TT - 4);
  // ---- prologue P1 (t = TT-2): L0 + L1 ----
  mfmaGRU(12, 18, 8, h0B, h1B, A1);        // h1(TT-1)
  mfmaGRU(0, 6, 0, xB, h0B, A0);           // h0(TT-2)
  gates(A1, h1C);
  gates(A0, h0C);
  h1B = packB(h1C); h0B = packB(h0C);
  rollX(TT - 5);
  // ---- prologue P2 (t = TT-3): L0 + L1 + E ----
  mfmaGRU(12, 18, 8, h0B, h1B, A1);        // h1(TT-2)
  e0 = mfma_(Wt[24], h1B, Bq[16]);         // e(TT-1) from h1(TT-1)
  e1 = mfma_(Wt[25], h1B, Bq[17]);
  mfmaGRU(0, 6, 0, xB, h0B, A0);           // h0(TT-3)
  gates(A1, h1C);
  gates(A0, h0C);
  silu(e0, e1, es);
  h1B = packB(h1C); h0B = packB(h0C); ef = packB(es);
  rollX(TT - 6);

  // ---- main loop: t = TT-4 .. 0, four stages, 1:20 interleave ----
#pragma unroll 2
  for (int t = TT - 4; t >= 0; --t) {
    mfmaGRU(12, 18, 8, h0B, h1B, A1);      // h1(t+1)
    e0 = mfma_(Wt[24], h1B, Bq[16]);       // e(t+2) from h1(t+2)
    e1 = mfma_(Wt[25], h1B, Bq[17]);
    o  = mfma_(Wt[26], ef, Bq[18]);        // o(t+3) from e(t+3)
    mfmaGRU(0, 6, 0, xB, h0B, A0);         // h0(t)
    gates(A1, h1C);
    gates(A0, h0C);
    silu(e0, e1, es);
    storeO(o, t + 3);
    h1B = packB(h1C);
    h0B = packB(h0C);
    ef  = packB(es);
    rollX(t - 3);
    // declarative schedule: 1 MFMA : 20 VALU, 27 groups; rest floats
#pragma unroll
    for (int kq = 0; kq < 27; ++kq) {
      __builtin_amdgcn_sched_group_barrier(0x008, 1, 0);   // 1 MFMA
      __builtin_amdgcn_sched_group_barrier(0x002, 20, 0);  // 20 VALU
    }
  }

  // ---- epilogue E1: h1(0), e(1), store(2) ----
  mfmaGRU(12, 18, 8, h0B, h1B, A1);
  e0 = mfma_(Wt[24], h1B, Bq[16]);
  e1 = mfma_(Wt[25], h1B, Bq[17]);
  o  = mfma_(Wt[26], ef, Bq[18]);
  gates(A1, h1C);
  silu(e0, e1, es);
  storeO(o, 2);
  h1B = packB(h1C); ef = packB(es);
  // ---- epilogue E2: e(0), store(1) ----
  e0 = mfma_(Wt[24], h1B, Bq[16]);
  e1 = mfma_(Wt[25], h1B, Bq[17]);
  o  = mfma_(Wt[26], ef, Bq[18]);
  silu(e0, e1, es);
  storeO(o, 1);
  ef = packB(es);
  // ---- epilogue E3: store(0) ----
  o = mfma_(Wt[26], ef, Bq[18]);
  storeO(o, 0);
}

// ---------------- launch ----------------
extern "C" void kernel_launch(void* const* d_in, const int* in_sizes, int n_in,
                              void* d_out, int out_size, void* d_ws,
                              size_t ws_size, hipStream_t stream) {
  const float* S   = (const float*)d_in[0];
  const float* gS  = (const float*)d_in[1];
  const float* hp0 = (const float*)d_in[5];
  const float* hd0 = (const float*)d_in[6];
  uint8_t* ws = (uint8_t*)d_ws;

  prep_both<<<2, 256, 0, stream>>>(
      (const float*)d_in[7],  (const float*)d_in[8],  (const float*)d_in[9],
      (const float*)d_in[10], (const float*)d_in[11], (const float*)d_in[12],
      (const float*)d_in[13], (const float*)d_in[14], (const float*)d_in[15],
      (const float*)d_in[16], (const float*)d_in[17], (const float*)d_in[18],
      (const float*)d_in[19], (const float*)d_in[20], (const float*)d_in[21],
      (const float*)d_in[22],
      (const float*)d_in[23], (const float*)d_in[24], (const float*)d_in[25],
      (const float*)d_in[26], (const float*)d_in[27], (const float*)d_in[28],
      (const float*)d_in[29], (const float*)d_in[30], (const float*)d_in[31],
      (const float*)d_in[32], (const float*)d_in[33], (const float*)d_in[34],
      (const float*)d_in[35], (const float*)d_in[36], (const float*)d_in[37],
      (const float*)d_in[38], ws);

  rnn_fused<<<dim3((BB / 16) * 2), dim3(64), 0, stream>>>(S, gS, hp0, hd0,
                                                          ws, (float*)d_out);
}

// Round 16
// 139.997 us; speedup vs baseline: 1.4108x; 1.4108x over previous
//
#include <hip/hip_runtime.h>
#include <hip/hip_bf16.h>
#include <stdint.h>

#define DI __device__ __forceinline__

typedef float f32x4 __attribute__((ext_vector_type(4)));
typedef float f32x2 __attribute__((ext_vector_type(2)));
typedef short bf16x8 __attribute__((ext_vector_type(8)));

constexpr int BB = 8192, TT = 128, DD = 16, HH = 32;
constexpr float kEPS = 1e-5f;
constexpr float kLOG2E = 1.44269504088896340736f;

// ---------------- helpers ----------------
DI float rcpf_(float x) { return __builtin_amdgcn_rcpf(x); }
DI float exp2f_(float x) { return __builtin_amdgcn_exp2f(x); }
DI float sigm(float x) { return rcpf_(1.0f + exp2f_(-kLOG2E * x)); }

DI uint32_t cvtpk(float lo, float hi) {
  uint32_t r;
  asm("v_cvt_pk_bf16_f32 %0, %1, %2" : "=v"(r) : "v"(lo), "v"(hi));
  return r;
}

DI f32x4 mfma_(bf16x8 a, bf16x8 b, f32x4 c) {
  return __builtin_amdgcn_mfma_f32_16x16x32_bf16(a, b, c, 0, 0, 0);
}

union U4 { uint4 q; bf16x8 v; uint32_t u[4]; };

// ---------------- weight prep (per net, device impl) ----------------
// pi k-permutation, exp2 pre-scaling, BN folded into emb, delta outW/outB
// pre-scaled by -log2e.
__device__ void prep_impl(const float* Wih0, const float* Whh0,
                          const float* bih0, const float* bhh0,
                          const float* Wih1, const float* Whh1,
                          const float* bih1, const float* bhh1,
                          const float* embW, const float* embB,
                          const float* bng, const float* bnb,
                          const float* bnm, const float* bnv,
                          const float* outW, const float* outB,
                          int outDim, uint8_t* wsbase) {
  int tid = threadIdx.x;
  uint16_t* W = (uint16_t*)wsbase;
  float* bias = (float*)(wsbase + 27648);
  auto cvt = [](float f) -> uint16_t {
    union { float f; uint32_t u; } v; v.f = f;
    uint32_t u = v.u;
    return (uint16_t)((u + 0x7FFF + ((u >> 16) & 1)) >> 16);  // RNE
  };
  const float oscale = (outDim == 16) ? -kLOG2E : 1.0f;
  for (int idx = tid; idx < 27 * 64; idx += 256) {
    int tile = idx >> 6, l = idx & 63, cc = l & 15, gg = l >> 4;
    uint16_t* dst = W + (size_t)idx * 8;
    if (tile < 24) {
      const float* mats[4] = {Wih0, Whh0, Wih1, Whh1};
      const float* src = mats[tile / 6];
      int sub = tile % 6;                   // r0 r1 z0 z1 n0 n1
      int row = sub * 16 + cc;
      float sc = (sub < 4) ? -kLOG2E : 2.0f * kLOG2E;
#pragma unroll
      for (int j = 0; j < 8; ++j) {
        int k = (j < 4) ? 4 * gg + j : 16 + 4 * gg + (j - 4);  // pi
        dst[j] = cvt(src[row * 32 + k] * sc);
      }
    } else if (tile < 26) {
      int row = (tile - 24) * 16 + cc;
      float a = bng[row] * rsqrtf(bnv[row] + kEPS);
#pragma unroll
      for (int j = 0; j < 8; ++j) {
        int k = (j < 4) ? 4 * gg + j : 16 + 4 * gg + (j - 4);  // pi
        dst[j] = cvt(embW[row * 32 + k] * a);
      }
    } else {
      int rrow = (cc < outDim) ? cc : 0;
      float sc = (cc < outDim) ? oscale : 0.0f;
#pragma unroll
      for (int j = 0; j < 8; ++j) {
        int k = (j < 4) ? 4 * gg + j : 16 + 4 * gg + (j - 4);  // pi
        dst[j] = cvt(outW[rrow * 32 + k] * sc);
      }
    }
  }
  for (int idx = tid; idx < 304; idx += 256) {
    int tile = idx >> 4, n = idx & 15;
    float v;
    if (tile < 8) {
      if (tile < 4)      v = (bih0[tile * 16 + n] + bhh0[tile * 16 + n]) * (-kLOG2E);
      else if (tile < 6) v = bih0[64 + (tile - 4) * 16 + n] * (2.0f * kLOG2E);
      else               v = bhh0[64 + (tile - 6) * 16 + n] * (2.0f * kLOG2E);
    } else if (tile < 16) {
      int tt = tile - 8;
      if (tt < 4)        v = (bih1[tt * 16 + n] + bhh1[tt * 16 + n]) * (-kLOG2E);
      else if (tt < 6)   v = bih1[64 + (tt - 4) * 16 + n] * (2.0f * kLOG2E);
      else               v = bhh1[64 + (tt - 6) * 16 + n] * (2.0f * kLOG2E);
    } else if (tile < 18) {
      int nn = (tile - 16) * 16 + n;
      float a = bng[nn] * rsqrtf(bnv[nn] + kEPS);
      v = a * (embB[nn] - bnm[nn]) + bnb[nn];
    } else {
      v = (n < outDim) ? outB[n] * oscale : 0.0f;
    }
    bias[idx] = v;
  }
}

// One launch, 2 blocks: block 0 = price net, block 1 = delta net.
__global__ void prep_both(
    const float* pW0, const float* pWh0, const float* pb0, const float* pbh0,
    const float* pW1, const float* pWh1, const float* pb1, const float* pbh1,
    const float* pe,  const float* peb,  const float* pg,  const float* pbb,
    const float* pm,  const float* pv,   const float* po,  const float* pob,
    const float* dW0, const float* dWh0, const float* db0, const float* dbh0,
    const float* dW1, const float* dWh1, const float* db1, const float* dbh1,
    const float* de,  const float* deb,  const float* dg,  const float* dbb,
    const float* dm,  const float* dv,   const float* doW, const float* dob,
    uint8_t* ws) {
  if (blockIdx.x == 0)
    prep_impl(pW0, pWh0, pb0, pbh0, pW1, pWh1, pb1, pbh1,
              pe, peb, pg, pbb, pm, pv, po, pob, 1, ws);
  else
    prep_impl(dW0, dWh0, db0, dbh0, dW1, dWh1, db1, dbh1,
              de, deb, dg, dbb, dm, dv, doW, dob, 16, ws + 32768);
}

// ---- fused RNN + heads: depth-4 pipeline, declarative 1:8 interleave -----
// One wave = 16 rows x 1 net. Iteration computes L0(t) | L1(t+1) | e(t+2) |
// o/store(t+3) — all MFMAs and all VALU/trans within an iteration are
// mutually independent, so sched_group_barrier emits {1 MFMA, 8 VALU} x 27:
// trans issue covers MFMA issue, no hard phase drains.
__global__ __launch_bounds__(64, 1) void rnn_fused(
    const float* __restrict__ S, const float* __restrict__ gS,
    const float* __restrict__ hp0, const float* __restrict__ hd0,
    const uint8_t* __restrict__ ws, float* __restrict__ out) {
  const int lane = threadIdx.x & 63;
  const int net = blockIdx.x & 1;                 // 0 = price, 1 = delta
  const int b0 = (blockIdx.x >> 1) * 16;
  const int c = lane & 15, g = lane >> 4;

  const uint16_t* W = (const uint16_t*)(ws + net * 32768);
  const float* bias = (const float*)(ws + net * 32768 + 27648);
  const float* hsrc = net ? hd0 : hp0;

  bf16x8 Wt[27];
#pragma unroll
  for (int t = 0; t < 27; ++t)
    Wt[t] = *(const bf16x8*)(W + (t * 64 + lane) * 8);
  f32x4 Bq[19];
#pragma unroll
  for (int t = 0; t < 19; ++t)
    Bq[t] = *(const f32x4*)(bias + t * 16 + 4 * g);

  auto packB = [&](const float (&v)[8]) -> bf16x8 {
    U4 t;
    t.u[0] = cvtpk(v[0], v[1]); t.u[1] = cvtpk(v[2], v[3]);
    t.u[2] = cvtpk(v[4], v[5]); t.u[3] = cvtpk(v[6], v[7]);
    return t.v;
  };

  auto mfmaGRU = [&](int wih, int whh, int bb, bf16x8 xf, bf16x8 hf,
                     f32x4 (&A)[8]) {
    A[0] = mfma_(Wt[wih + 0], xf, Bq[bb + 0]); A[0] = mfma_(Wt[whh + 0], hf, A[0]);
    A[1] = mfma_(Wt[wih + 1], xf, Bq[bb + 1]); A[1] = mfma_(Wt[whh + 1], hf, A[1]);
    A[2] = mfma_(Wt[wih + 2], xf, Bq[bb + 2]); A[2] = mfma_(Wt[whh + 2], hf, A[2]);
    A[3] = mfma_(Wt[wih + 3], xf, Bq[bb + 3]); A[3] = mfma_(Wt[whh + 3], hf, A[3]);
    A[4] = mfma_(Wt[wih + 4], xf, Bq[bb + 4]);
    A[5] = mfma_(Wt[wih + 5], xf, Bq[bb + 5]);
    A[6] = mfma_(Wt[whh + 4], hf, Bq[bb + 6]);
    A[7] = mfma_(Wt[whh + 5], hf, Bq[bb + 7]);
  };

  auto gates = [&](const f32x4 (&A)[8], float (&hC)[8]) {
    const f32x2 one = {1.0f, 1.0f};
#pragma unroll
    for (int r = 0; r < 4; ++r) {
      f32x2 ra = {A[0][r], A[1][r]};
      f32x2 za = {A[2][r], A[3][r]};
      f32x2 ni = {A[4][r], A[5][r]};
      f32x2 nh = {A[6][r], A[7][r]};
      f32x2 hv = {hC[r], hC[4 + r]};
      f32x2 era = {exp2f_(ra[0]), exp2f_(ra[1])};
      f32x2 t1 = one + era;
      f32x2 rg = {rcpf_(t1[0]), rcpf_(t1[1])};
      f32x2 w = ni + rg * nh;
      f32x2 En = {exp2f_(w[0]), exp2f_(w[1])};
      f32x2 Ez = {exp2f_(za[0]), exp2f_(za[1])};
      f32x2 num = (hv - Ez) + En * (hv + Ez);
      f32x2 den = (one + En) * (one + Ez);
      f32x2 rd = {rcpf_(den[0]), rcpf_(den[1])};
      f32x2 res = num * rd;
      hC[r] = res[0]; hC[4 + r] = res[1];
    }
  };

  auto silu = [&](const f32x4& e0, const f32x4& e1, float (&es)[8]) {
#pragma unroll
    for (int r = 0; r < 4; ++r) {
      float a = e0[r], b = e1[r];
      es[r]     = a * sigm(a);
      es[4 + r] = b * sigm(b);
    }
  };

  auto storeO = [&](const f32x4& o, int th) {
    if (net == 0) {
      if (lane < 16) out[(size_t)(b0 + c) * TT + th] = o[0];
    } else {
      f32x4 so;                       // outW prescaled: sig = rcp(1+exp2)
#pragma unroll
      for (int r = 0; r < 4; ++r) so[r] = rcpf_(1.0f + exp2f_(o[r]));
      *(f32x4*)(out + (size_t)BB * TT +
                ((size_t)(b0 + c) * TT + th) * DD + 4 * g) = so;
    }
  };

  auto loadState = [&](const float* row, float (&hC)[8]) -> bf16x8 {
    f32x4 a = *(const f32x4*)(row + 4 * g);
    f32x4 b = *(const f32x4*)(row + 16 + 4 * g);
#pragma unroll
    for (int r = 0; r < 4; ++r) { hC[r] = a[r]; hC[4 + r] = b[r]; }
    U4 t;
    t.u[0] = cvtpk(a[0], a[1]); t.u[1] = cvtpk(a[2], a[3]);
    t.u[2] = cvtpk(b[0], b[1]); t.u[3] = cvtpk(b[2], b[3]);
    return t.v;
  };

  auto mkX = [&](f32x4 sv, float gsv) -> bf16x8 {
    uint32_t pkg = cvtpk(gsv, gsv);
    U4 t;
    t.u[0] = cvtpk(sv[0], sv[1]);
    t.u[1] = cvtpk(sv[2], sv[3]);
    t.u[2] = pkg;
    t.u[3] = pkg;
    return t.v;
  };

  const float* Sbase  = S  + (size_t)(b0 + c) * TT * DD + 4 * g;
  const float* gSbase = gS + (size_t)(b0 + c) * TT;

  // pipeline state
  float h0C[8], h1C[8], es[8];
  bf16x8 h0B = loadState(hsrc + (size_t)(b0 + c) * HH, h0C);
  bf16x8 h1B = loadState(hsrc + ((size_t)BB + b0 + c) * HH, h1C);
  bf16x8 ef, xB;
  f32x4 A0[8], A1[8], e0, e1, o;

  // x rolling registers: xB = x(t); xr0 = raw x(t-1); xr1 = raw x(t-2)
  f32x4 xr0, xr1;
  float gr0, gr1;
  xB  = mkX(*(const f32x4*)(Sbase + (size_t)(TT - 1) * DD), gSbase[TT - 1]);
  xr0 = *(const f32x4*)(Sbase + (size_t)(TT - 2) * DD); gr0 = gSbase[TT - 2];
  xr1 = *(const f32x4*)(Sbase + (size_t)(TT - 3) * DD); gr1 = gSbase[TT - 3];
  auto rollX = [&](int tn) {
    xB = mkX(xr0, gr0);
    xr0 = xr1; gr0 = gr1;
    if (tn < 0) tn = 0;
    xr1 = *(const f32x4*)(Sbase + (size_t)tn * DD); gr1 = gSbase[tn];
  };

  // ---- prologue P0 (t = TT-1): L0 only ----
  mfmaGRU(0, 6, 0, xB, h0B, A0);
  gates(A0, h0C);
  h0B = packB(h0C);
  rollX(TT - 4);
  // ---- prologue P1 (t = TT-2): L0 + L1 ----
  mfmaGRU(12, 18, 8, h0B, h1B, A1);        // h1(TT-1)
  mfmaGRU(0, 6, 0, xB, h0B, A0);           // h0(TT-2)
  gates(A1, h1C);
  gates(A0, h0C);
  h1B = packB(h1C); h0B = packB(h0C);
  rollX(TT - 5);
  // ---- prologue P2 (t = TT-3): L0 + L1 + E ----
  mfmaGRU(12, 18, 8, h0B, h1B, A1);        // h1(TT-2)
  e0 = mfma_(Wt[24], h1B, Bq[16]);         // e(TT-1) from h1(TT-1)
  e1 = mfma_(Wt[25], h1B, Bq[17]);
  mfmaGRU(0, 6, 0, xB, h0B, A0);           // h0(TT-3)
  gates(A1, h1C);
  gates(A0, h0C);
  silu(e0, e1, es);
  h1B = packB(h1C); h0B = packB(h0C); ef = packB(es);
  rollX(TT - 6);

  // ---- main loop: t = TT-4 .. 0, all four stages, 1:8 interleave ----
#pragma unroll 2
  for (int t = TT - 4; t >= 0; --t) {
    mfmaGRU(12, 18, 8, h0B, h1B, A1);      // h1(t+1)
    e0 = mfma_(Wt[24], h1B, Bq[16]);       // e(t+2) from h1(t+2)
    e1 = mfma_(Wt[25], h1B, Bq[17]);
    o  = mfma_(Wt[26], ef, Bq[18]);        // o(t+3) from e(t+3)
    mfmaGRU(0, 6, 0, xB, h0B, A0);         // h0(t)
    gates(A1, h1C);
    gates(A0, h0C);
    silu(e0, e1, es);
    storeO(o, t + 3);
    h1B = packB(h1C);
    h0B = packB(h0C);
    ef  = packB(es);
    rollX(t - 3);
    // declarative schedule: 1 MFMA : 8 VALU, 27 groups; rest floats
#pragma unroll
    for (int kq = 0; kq < 27; ++kq) {
      __builtin_amdgcn_sched_group_barrier(0x008, 1, 0);  // 1 MFMA
      __builtin_amdgcn_sched_group_barrier(0x002, 8, 0);  // 8 VALU
    }
  }

  // ---- epilogue E1: h1(0), e(1), store(2) ----
  mfmaGRU(12, 18, 8, h0B, h1B, A1);
  e0 = mfma_(Wt[24], h1B, Bq[16]);
  e1 = mfma_(Wt[25], h1B, Bq[17]);
  o  = mfma_(Wt[26], ef, Bq[18]);
  gates(A1, h1C);
  silu(e0, e1, es);
  storeO(o, 2);
  h1B = packB(h1C); ef = packB(es);
  // ---- epilogue E2: e(0), store(1) ----
  e0 = mfma_(Wt[24], h1B, Bq[16]);
  e1 = mfma_(Wt[25], h1B, Bq[17]);
  o  = mfma_(Wt[26], ef, Bq[18]);
  silu(e0, e1, es);
  storeO(o, 1);
  ef = packB(es);
  // ---- epilogue E3: store(0) ----
  o = mfma_(Wt[26], ef, Bq[18]);
  storeO(o, 0);
}

// ---------------- launch ----------------
extern "C" void kernel_launch(void* const* d_in, const int* in_sizes, int n_in,
                              void* d_out, int out_size, void* d_ws,
                              size_t ws_size, hipStream_t stream) {
  const float* S   = (const float*)d_in[0];
  const float* gS  = (const float*)d_in[1];
  const float* hp0 = (const float*)d_in[5];
  const float* hd0 = (const float*)d_in[6];
  uint8_t* ws = (uint8_t*)d_ws;

  prep_both<<<2, 256, 0, stream>>>(
      (const float*)d_in[7],  (const float*)d_in[8],  (const float*)d_in[9],
      (const float*)d_in[10], (const float*)d_in[11], (const float*)d_in[12],
      (const float*)d_in[13], (const float*)d_in[14], (const float*)d_in[15],
      (const float*)d_in[16], (const float*)d_in[17], (const float*)d_in[18],
      (const float*)d_in[19], (const float*)d_in[20], (const float*)d_in[21],
      (const float*)d_in[22],
      (const float*)d_in[23], (const float*)d_in[24], (const float*)d_in[25],
      (const float*)d_in[26], (const float*)d_in[27], (const float*)d_in[28],
      (const float*)d_in[29], (const float*)d_in[30], (const float*)d_in[31],
      (const float*)d_in[32], (const float*)d_in[33], (const float*)d_in[34],
      (const float*)d_in[35], (const float*)d_in[36], (const float*)d_in[37],
      (const float*)d_in[38], ws);

  rnn_fused<<<dim3((BB / 16) * 2), dim3(64), 0, stream>>>(S, gS, hp0, hd0,
                                                          ws, (float*)d_out);
}